// Round 14
// baseline (506.271 us; speedup 1.0000x reference)
//
#include <hip/hip_runtime.h>
#include <hip/hip_bf16.h>
#include <math.h>

// Problem constants
#define NROWS   8192      // 2*B
#define HLEN    50
#define SLEN    32
#define NPAIR   4096

typedef __attribute__((ext_vector_type(8))) short   short8;
typedef __attribute__((ext_vector_type(8))) __bf16  b8;     // MFMA operand type
typedef __attribute__((ext_vector_type(4))) float   f32x4;
typedef unsigned short us;

// ---- bf16 arena offsets (elements) for small fp32 tensors ----
#define A_GV_B1    0
#define A_GV_B2    128
#define A_ATTH_B1  256
#define A_ATTH_W2  384
#define A_ENC_W    512
#define A_ENC_B    33280
#define A_ATTS_B1  33408
#define A_ATTS_W2  33536
#define A_SOC_W    33664
#define A_SOC_B    66432
#define A_ATTN_WA  66560
#define A_ATTN_BA  82944
#define A_FC1_W    83072
#define A_FC1_B    99456
#define A_BN1_G    99584
#define A_BN1_B    99712
#define A_FC2_W    99840
#define A_FC2_B    116224
#define A_EFC1_W   116352
#define A_EFC1_B   149120
#define A_BN2_G    149248
#define A_BN2_B    149376
#define A_EFC2_W   149504
#define A_EFC2_B   165888
#define A_TOTAL    166016

// workspace layout (bytes)
#define WS_HR    0u          // 8192*128 bf16 = 2097152
#define WS_Z     2097152u    // 4096*128 f32  = 2097152
#define WS_ST    4194304u    // 256 f32 + pad
#define WS_WP1   4195328u    // 32768 bf16
#define WS_WP2   4260864u    // 16384 bf16
#define WS_WPA   4293632u    // 32768 bf16
#define WS_WPS   4359168u    // 32768 bf16
#define WS_AR    4424704u    // 166016 bf16 -> end 4756736
#define WS_UB    4757504u    // 100000*128 bf16 = 25600000
#define WS_VB    30357504u   // 50000*128 bf16  = 12800000
#define WS_RB    43157504u   // 10*128 bf16     = 2560
#define WS2_NEED 43160064u

// k_prep block ranges (256 threads each)
#define PB_CVT   649         // ceil(166016/256)
#define PB_PACK  56          // 14336/256
#define PB_TAB   9376        // ceil(2400160/256)

__device__ __forceinline__ float b2f(us u){
  unsigned int x = ((unsigned int)u) << 16; float f;
  __builtin_memcpy(&f, &x, 4); return f;
}
// accurate RNE (one-time weight/table conversion)
__device__ __forceinline__ us f2b(float f){
  unsigned int x; __builtin_memcpy(&x, &f, 4);
  return (us)((x + 0x7fffu + ((x >> 16) & 1u)) >> 16);
}
// cheap round-half-up (activation hot path)
__device__ __forceinline__ us f2bc(float f){
  unsigned int x; __builtin_memcpy(&x, &f, 4);
  return (us)((x + 0x8000u) >> 16);
}
__device__ __forceinline__ float relu(float x){ return 0.5f * (x + fabsf(x)); }

__device__ __forceinline__ b8 f8_to_b8(const float* f){
  short8 v;
#pragma unroll
  for (int j = 0; j < 8; ++j) v[j] = (short)f2bc(f[j]);
  return __builtin_bit_cast(b8, v);
}

// ---- async global->LDS staging (16B per lane, wave-uniform LDS base) ----
typedef __attribute__((address_space(3))) unsigned char lds_b;
typedef const __attribute__((address_space(1))) unsigned char glob_b;

__device__ __forceinline__ void gll16(const us* g, us* d){
  __builtin_amdgcn_global_load_lds((glob_b*)g, (lds_b*)d, 16, 0, 0);
}

// Stage one 8KB K-slice of lane-linear packed weights into ring buffer p
// (p in 0..2), 8 waves cooperating: wave w8 copies us range [w8*512, +512)
// with ONE global_load_lds (16B/lane) -> 1 vmem op per wave per stage.
__device__ __forceinline__ void stage8k(const us* __restrict__ W, us* sB,
                                        int w8, int l, int ks, int p){
  const us* src = W + ((long)ks << 12) + (w8 << 9) + (l << 3);
  us* dst = sB + p * 4096 + (w8 << 9);
  gll16(src, dst);
}

// Depth-2 counted-wait phase boundary (T4: never drain to 0 mid-loop).
// Each wave has <=2 stages outstanding; vmcnt(1) completes the OLDEST
// (this phase's buffer) while the next stage stays in flight across the
// barrier. sched_barrier(0) pins pre-barrier MFMAs above (rule #18).
#define PHASE_SYNC() do {                                   \
    asm volatile("s_waitcnt vmcnt(1)" ::: "memory");        \
    __builtin_amdgcn_s_barrier();                           \
    asm volatile("" ::: "memory");                          \
    __builtin_amdgcn_sched_barrier(0);                      \
  } while (0)

// ---- ONE preprocessing launch: cvt arena + pack MFMA weights + bf16 tables ----
struct Prep {
  const void* cp[24]; unsigned coff[25];            // cvt sources
  const float *W1, *W2, *WA, *WS;                   // pack sources
  const float *u2e, *v2e, *r2e;                     // table sources
};
__global__ void k_prep(Prep pr, us* __restrict__ AR,
                       us* __restrict__ Wp1, us* __restrict__ Wp2,
                       us* __restrict__ WpA, us* __restrict__ WpS,
                       us* __restrict__ Ub, us* __restrict__ Vb,
                       us* __restrict__ Rb, int do_tab)
{
  const int b = blockIdx.x, t = threadIdx.x;
  if (b < PB_CVT){                                  // ---- arena cvt ----
    int i = b * 256 + t;
    if (i >= A_TOTAL) return;
    int s = 0;
    while (i >= (int)pr.coff[s + 1]) ++s;
    AR[i] = f2b(((const float*)pr.cp[s])[i - (int)pr.coff[s]]);
  } else if (b < PB_CVT + PB_PACK){                 // ---- MFMA pack ----
    int g = (b - PB_CVT) * 256 + t;                 // g < 14336 always
    const float* W; us* Wp; int loc;
    if      (g <  4096){ W = pr.W1; Wp = Wp1; loc = g; }
    else if (g <  6144){ W = pr.W2; Wp = Wp2; loc = g - 4096; }
    else if (g < 10240){ W = pr.WA; Wp = WpA; loc = g - 6144; }
    else               { W = pr.WS; Wp = WpS; loc = g - 10240; }
    int lane16 = loc & 15, quad = (loc >> 4) & 3, nt = (loc >> 6) & 7, kseg = loc >> 9;
#pragma unroll
    for (int j = 0; j < 8; ++j)
      Wp[(long)loc * 8 + j] = f2b(W[(kseg * 32 + quad * 8 + j) * 128 + nt * 16 + lane16]);
  } else {                                          // ---- bf16 tables ----
    if (!do_tab) return;
    int i = (b - PB_CVT - PB_PACK) * 256 + t;
    const float* s; us* d; int loc;
    if      (i < 1600000){ s = pr.u2e; d = Ub; loc = i; }
    else if (i < 2400000){ s = pr.v2e; d = Vb; loc = i - 1600000; }
    else if (i < 2400160){ s = pr.r2e; d = Rb; loc = i - 2400000; }
    else return;
    const float* sp = s + (long)loc * 8;
    short8 w;
#pragma unroll
    for (int j = 0; j < 8; ++j) w[j] = (short)f2b(sp[j]);
    *(short8*)(d + (long)loc * 8) = w;
  }
}

// ============ fused history+social path: one block per TWO rows ============
// Ring buffer g%3; stage for g+2 issued at phase g (depth-2).
// NOTE (R12 lesson): do NOT fuse the k7 head in here — the head's many-block
// TLP as a separate kernel far outweighs the 2MB HR round-trip it saves.
template<int TAB>
__global__ __launch_bounds__(512, 4)
void k_fused(const int* __restrict__ items, const int* __restrict__ ratings,
             const void* __restrict__ vt, const void* __restrict__ rt,
             const int* __restrict__ uids, const void* __restrict__ ut,
             const int* __restrict__ soc,
             const us* __restrict__ Wp1, const us* __restrict__ Wp2,
             const us* __restrict__ WpA, const us* __restrict__ WpS,
             const us* __restrict__ AR, us* __restrict__ HR)
{
  const int t = threadIdx.x;
  const int rr = t >> 8, tt = t & 255;          // row group, id within group
  const int r = blockIdx.x * 2 + rr;
  const int w = tt >> 6;                        // wave within row group 0..3
  const int w8 = t >> 6;                        // global wave 0..7 (staging)
  const int l = t & 63, lane16 = l & 15, quad = l >> 4;
  const int tc = tt & 127, th = tt >> 7;        // split-k id within row
  const long ubase = (long)uids[r] * 128;

  __shared__ __align__(16) us sX[2][64 * 136];  // per-row X1->X2; later sN
  __shared__ __align__(16) us sB[3 * 4096];     // ring of 3 x 8KB B slices
  __shared__ float esh[2][64], a_sh[2][64], part[2][256], xin[2][256];

  // prologue: slices 0,1 in flight before the A-fragment gather
  stage8k(Wp1, sB, w8, l, 0, 0);                // g=0 -> buf 0
  stage8k(Wp1, sB, w8, l, 1, 1);                // g=1 -> buf 1

  const int arow = w * 16 + lane16;
  const bool av = arow < HLEN;
  const int it_i = av ? items[r * HLEN + arow]   : 0;
  const int rt_i = av ? ratings[r * HLEN + arow] : 0;

  // ---- A fragments for GEMM1 (direct gather) ----
  b8 af[8];
#pragma unroll
  for (int ks = 0; ks < 8; ++ks){
    b8 a;
    if constexpr (TAB){
      const us* ap = (ks < 4)
          ? (const us*)vt + (long)it_i * 128 + ks * 32 + quad * 8
          : (const us*)rt + (long)rt_i * 128 + (ks - 4) * 32 + quad * 8;
      a = *(const b8*)ap;
    } else {
      const float* ap = (ks < 4)
          ? (const float*)vt + (long)it_i * 128 + ks * 32 + quad * 8
          : (const float*)rt + (long)rt_i * 128 + (ks - 4) * 32 + quad * 8;
      a = f8_to_b8(ap);
    }
    if (!av) a = __builtin_bit_cast(b8, (short8)0);
    af[ks] = a;
  }
  // u-row fragments (broadcast row; reused in GEMM3 + soc GEMM)
  b8 uf[4];
#pragma unroll
  for (int ks = 0; ks < 4; ++ks){
    if constexpr (TAB)
      uf[ks] = *(const b8*)((const us*)ut + ubase + ks * 32 + quad * 8);
    else
      uf[ks] = f8_to_b8((const float*)ut + ubase + ks * 32 + quad * 8);
  }

  // ---- GEMM1: X1 = relu([v|r] @ W1 + b1), K=256, g=0..7 ----
  {
    f32x4 acc[8];
#pragma unroll
    for (int nt = 0; nt < 8; ++nt) acc[nt] = (f32x4){0.f,0.f,0.f,0.f};
#pragma unroll
    for (int ks = 0; ks < 8; ++ks){
      PHASE_SYNC();                             // oldest stage (ks) landed
      if      (ks < 6)  stage8k(Wp1, sB, w8, l, ks + 2, (ks + 2) % 3);
      else if (ks == 6) stage8k(Wp2, sB, w8, l, 0, 2);   // g'=8  -> buf 2
      else              stage8k(Wp2, sB, w8, l, 1, 0);   // g'=9  -> buf 0
      const us* bb = sB + (ks % 3) * 4096 + l * 8;
#pragma unroll
      for (int nt = 0; nt < 8; ++nt)
        acc[nt] = __builtin_amdgcn_mfma_f32_16x16x32_bf16(
            af[ks], *(const b8*)(bb + nt * 512), acc[nt], 0, 0, 0);
    }
#pragma unroll
    for (int nt = 0; nt < 8; ++nt){
      int col = nt * 16 + lane16;
      float bbv = b2f(AR[A_GV_B1 + col]);
#pragma unroll
      for (int rg = 0; rg < 4; ++rg)
        sX[rr][(w * 16 + quad * 4 + rg) * 136 + col] = f2bc(relu(acc[nt][rg] + bbv));
    }
  }
  // no barrier: each wave reads/writes only its own 16-row slice of sX[rr]

  // ---- GEMM2: X2 = relu(X1 @ W2 + b2), K=128, g=8..11, in place ----
  {
    b8 a2[4];
#pragma unroll
    for (int ks = 0; ks < 4; ++ks)
      a2[ks] = *(const b8*)(sX[rr] + arow * 136 + ks * 32 + quad * 8);
    f32x4 acc[8];
#pragma unroll
    for (int nt = 0; nt < 8; ++nt) acc[nt] = (f32x4){0.f,0.f,0.f,0.f};
#pragma unroll
    for (int ks = 0; ks < 4; ++ks){
      PHASE_SYNC();
      if      (ks < 2)  stage8k(Wp2, sB, w8, l, ks + 2, (ks + 10) % 3); // g'=10,11
      else if (ks == 2) stage8k(WpA, sB, w8, l, 0, 0);   // g'=12 -> buf 0
      else              stage8k(WpA, sB, w8, l, 1, 1);   // g'=13 -> buf 1
      const us* bb = sB + ((8 + ks) % 3) * 4096 + l * 8;
#pragma unroll
      for (int nt = 0; nt < 8; ++nt)
        acc[nt] = __builtin_amdgcn_mfma_f32_16x16x32_bf16(
            a2[ks], *(const b8*)(bb + nt * 512), acc[nt], 0, 0, 0);
    }
#pragma unroll
    for (int nt = 0; nt < 8; ++nt){
      int col = nt * 16 + lane16;
      float bbv = b2f(AR[A_GV_B2 + col]);
#pragma unroll
      for (int rg = 0; rg < 4; ++rg)
        sX[rr][(w * 16 + quad * 4 + rg) * 136 + col] = f2bc(relu(acc[nt][rg] + bbv));
    }
  }

  // ---- GEMM3: e = relu([X2|u] @ WA + bA) @ w2, K=256, g=12..19 ----
  {
    b8 a3[8];
#pragma unroll
    for (int ks = 0; ks < 4; ++ks)
      a3[ks] = *(const b8*)(sX[rr] + arow * 136 + ks * 32 + quad * 8);
#pragma unroll
    for (int ks = 0; ks < 4; ++ks) a3[4 + ks] = uf[ks];
    f32x4 acc[8];
#pragma unroll
    for (int nt = 0; nt < 8; ++nt) acc[nt] = (f32x4){0.f,0.f,0.f,0.f};
#pragma unroll
    for (int ks = 0; ks < 8; ++ks){
      PHASE_SYNC();
      if      (ks < 6)  stage8k(WpA, sB, w8, l, ks + 2, (ks + 14) % 3);
      else if (ks == 6) stage8k(WpS, sB, w8, l, 0, 2);   // g'=20 -> buf 2
      else              stage8k(WpS, sB, w8, l, 1, 0);   // g'=21 -> buf 0
      const us* bb = sB + ((12 + ks) % 3) * 4096 + l * 8;
#pragma unroll
      for (int nt = 0; nt < 8; ++nt)
        acc[nt] = __builtin_amdgcn_mfma_f32_16x16x32_bf16(
            a3[ks], *(const b8*)(bb + nt * 512), acc[nt], 0, 0, 0);
    }
    float pr[4] = {0.f, 0.f, 0.f, 0.f};
#pragma unroll
    for (int nt = 0; nt < 8; ++nt){             // hoisted bias/w2 loads
      int col = nt * 16 + lane16;
      float bbv = b2f(AR[A_ATTH_B1 + col]);
      float wwv = b2f(AR[A_ATTH_W2 + col]);
#pragma unroll
      for (int rg = 0; rg < 4; ++rg)
        pr[rg] += relu(acc[nt][rg] + bbv) * wwv;
    }
#pragma unroll
    for (int rg = 0; rg < 4; ++rg){
      float p = pr[rg];
      p += __shfl_xor(p, 1, 64);
      p += __shfl_xor(p, 2, 64);
      p += __shfl_xor(p, 4, 64);
      p += __shfl_xor(p, 8, 64);
      if (lane16 == 0) esh[rr][w * 16 + quad * 4 + rg] = p;
    }
  }
  __syncthreads();                              // B1: esh complete (+WpS s0,s1 land)

  if (tt < 64){                                 // softmax over 50 (waves 0,4)
    float e = (tt < HLEN) ? esh[rr][tt] : -1e30f;
    float mx = e;
#pragma unroll
    for (int m = 1; m < 64; m <<= 1) mx = fmaxf(mx, __shfl_xor(mx, m, 64));
    float ex = (tt < HLEN) ? expf(e - mx) : 0.f;
    float s = ex;
#pragma unroll
    for (int m = 1; m < 64; m <<= 1) s += __shfl_xor(s, m, 64);
    if (tt < HLEN) a_sh[rr][tt] = ex / s;
  }
  __syncthreads();                              // B2: a_sh

  {                                             // agg split-k (25 rows/half)
    float s = 0.f;
    for (int h = th * 25; h < th * 25 + 25; ++h)
      s += a_sh[rr][h] * b2f(sX[rr][h * 136 + tc]);
    part[rr][tt] = s;
  }
  __syncthreads();                              // B3: part
  if (tt < 128){
    xin[rr][tt] = TAB ? b2f(((const us*)ut)[ubase + tt]) : ((const float*)ut)[ubase + tt];
    xin[rr][128 + tt] = part[rr][tt] + part[rr][128 + tt];
  }
  __syncthreads();                              // B4: xin

  // enc split-k (column-major AR reads: coalesced across lanes) + soc gather
  {
    float s0 = 0.f, s1 = 0.f;
    const int kb = th * 128;
    for (int k = 0; k < 128; k += 2){
      s0 += xin[rr][kb + k]     * b2f(AR[A_ENC_W + (kb + k)     * 128 + tc]);
      s1 += xin[rr][kb + k + 1] * b2f(AR[A_ENC_W + (kb + k + 1) * 128 + tc]);
    }
    part[rr][tt] = s0 + s1;
#pragma unroll
    for (int it = 0; it < 2; ++it){             // sN: 32 x 128 gather per row
      int idx = tt * 8 + it * 2048;
      int row = idx >> 7, col = idx & 127;
      long eb = (long)soc[r * SLEN + row] * 128 + col;
      short8 v;
      if constexpr (TAB) v = *(const short8*)((const us*)ut + eb);
      else               v = __builtin_bit_cast(short8, f8_to_b8((const float*)ut + eb));
      *(short8*)(sX[rr] + row * 136 + col) = v;
    }
  }
  __syncthreads();                              // B5: enc part + sN staged

  float hhv = 0.f;                              // HH value (register, tt<128)
  if (tt < 128)
    hhv = relu(part[rr][tt] + part[rr][128 + tt] + b2f(AR[A_ENC_B + tt]));

  // ---- soc GEMM: es = relu([nf|u] @ WS + bS) @ w2s, M=32, K=256, g=20..27 ----
  {
    const int mt = w & 1, nh = w >> 1;
    const int arow2 = mt * 16 + lane16;
    b8 aS[8];
#pragma unroll
    for (int ks = 0; ks < 4; ++ks)
      aS[ks] = *(const b8*)(sX[rr] + arow2 * 136 + ks * 32 + quad * 8);
#pragma unroll
    for (int ks = 0; ks < 4; ++ks) aS[4 + ks] = uf[ks];
    f32x4 acc[4];
#pragma unroll
    for (int nt = 0; nt < 4; ++nt) acc[nt] = (f32x4){0.f,0.f,0.f,0.f};
#pragma unroll
    for (int ks = 0; ks < 8; ++ks){
      PHASE_SYNC();
      if (ks < 6) stage8k(WpS, sB, w8, l, ks + 2, (ks + 22) % 3);
      const us* bb = sB + ((20 + ks) % 3) * 4096 + (nh << 11) + l * 8;  // nh half
#pragma unroll
      for (int nt = 0; nt < 4; ++nt)
        acc[nt] = __builtin_amdgcn_mfma_f32_16x16x32_bf16(
            aS[ks], *(const b8*)(bb + nt * 512), acc[nt], 0, 0, 0);
    }
    float pr[4] = {0.f, 0.f, 0.f, 0.f};
#pragma unroll
    for (int nt = 0; nt < 4; ++nt){             // hoisted bias/w2 loads
      int n = nh * 64 + nt * 16 + lane16;
      float bbv = b2f(AR[A_ATTS_B1 + n]);
      float wwv = b2f(AR[A_ATTS_W2 + n]);
#pragma unroll
      for (int rg = 0; rg < 4; ++rg)
        pr[rg] += relu(acc[nt][rg] + bbv) * wwv;
    }
#pragma unroll
    for (int rg = 0; rg < 4; ++rg){
      float p = pr[rg];
      p += __shfl_xor(p, 1, 64);
      p += __shfl_xor(p, 2, 64);
      p += __shfl_xor(p, 4, 64);
      p += __shfl_xor(p, 8, 64);
      if (lane16 == 0) esh[rr][nh * 32 + mt * 16 + quad * 4 + rg] = p;
    }
  }
  __syncthreads();                              // B6: soc esh

  if (tt < 32){                                 // softmax over 32
    float e = esh[rr][tt] + esh[rr][32 + tt];
    float mx = e;
#pragma unroll
    for (int m = 1; m < 32; m <<= 1) mx = fmaxf(mx, __shfl_xor(mx, m, 32));
    float ex = expf(e - mx);
    float s = ex;
#pragma unroll
    for (int m = 1; m < 32; m <<= 1) s += __shfl_xor(s, m, 32);
    a_sh[rr][tt] = ex / s;
  }
  __syncthreads();                              // B7

  {                                             // agg_s split-k
    float s = 0.f;
    for (int h = th * 16; h < th * 16 + 16; ++h)
      s += a_sh[rr][h] * b2f(sX[rr][h * 136 + tc]);
    part[rr][tt] = s;
  }
  __syncthreads();                              // B8
  if (tt < 128){
    xin[rr][tt]       = hhv;
    xin[rr][128 + tt] = part[rr][tt] + part[rr][128 + tt];
  }
  __syncthreads();                              // B9

  {                                             // soc layer split-k (column AR)
    float s0 = 0.f, s1 = 0.f;
    const int kb = th * 128;
    for (int k = 0; k < 128; k += 2){
      s0 += xin[rr][kb + k]     * b2f(AR[A_SOC_W + (kb + k)     * 128 + tc]);
      s1 += xin[rr][kb + k + 1] * b2f(AR[A_SOC_W + (kb + k + 1) * 128 + tc]);
    }
    part[rr][tt] = s0 + s1;
  }
  __syncthreads();                              // B10
  if (tt < 128)
    HR[(long)r * 128 + tt] =
        f2bc(relu(part[rr][tt] + part[rr][128 + tt] + b2f(AR[A_SOC_B + tt])));
}

// ---------------- K7 v2: head, 2 pairs/block, LDS-staged weights ----------------
// 2048 blocks x 256 threads. Thread (d = t&127, h = t>>7) computes BOTH rows of
// pair p = 2*bid + h. Each 32KB weight matrix is staged ONCE into LDS via
// global_load_lds and shared by both pairs (weight L2 traffic halves vs R8;
// inner loads move from ~200cy L2 to LDS). Accumulation chains, reduction
// lanes, softmax/LN formulas and rounding identical -> bit-exact.
__global__ __launch_bounds__(256)
void k7_head(const us* __restrict__ HR, const us* __restrict__ AR,
             float* __restrict__ OUT, float* __restrict__ Z)
{
  const int t = threadIdx.x;
  const int d = t & 127, h = t >> 7;           // column, pair-half
  const int w4 = t >> 6, l = t & 63;           // wave 0..3, lane
  const long p = (long)blockIdx.x * 2 + h;     // pair index

  __shared__ __align__(16) us sW[16384];       // 32KB staged weight matrix
  __shared__ float hp[2][2][128];              // [h][row][d]
  __shared__ float ry[2][2][128];
  __shared__ float csh[2][256];
  __shared__ float sred[2][2][2];              // [h][waveInHalf][row]

  // issue attn_wa staging first — overlaps the hp loads below
  {
    const us* src = AR + A_ATTN_WA;
#pragma unroll
    for (int i = 0; i < 8; ++i)
      gll16(src + w4 * 4096 + i * 512 + l * 8, sW + w4 * 4096 + i * 512);
  }

  // hp: HR rows 4*bid .. 4*bid+3; layout [h][row][d] is linear in v
  {
    const long base = (long)blockIdx.x * 512;
    for (int v = t; v < 512; v += 256)
      ((float*)hp)[v] = b2f(HR[base + v]);
  }
  __syncthreads();                             // attn_wa staged (vmcnt drain) + hp

  // ---- attn mat-vec (sW = attn_wa), both rows of pair h ----
  float a0 = 0.f, a1 = 0.f, b0 = 0.f, b1 = 0.f;
  for (int k = 0; k < 128; k += 2){
    float w0 = b2f(sW[k * 128 + d]);
    float w1 = b2f(sW[(k + 1) * 128 + d]);
    a0 += hp[h][0][k] * w0;  a1 += hp[h][0][k + 1] * w1;
    b0 += hp[h][1][k] * w0;  b1 += hp[h][1][k + 1] * w1;
  }
  float ba = b2f(AR[A_ATTN_BA + d]);
  float p0 = tanhf(a0 + a1) * ba;
  float p1 = tanhf(b0 + b1) * ba;
#pragma unroll
  for (int m = 1; m < 64; m <<= 1){ p0 += __shfl_xor(p0, m, 64); p1 += __shfl_xor(p1, m, 64); }
  if (l == 0){ sred[h][w4 & 1][0] = p0; sred[h][w4 & 1][1] = p1; }
  __syncthreads();                             // attn reads done + sred ready

  // stage fc1_w (overwrites sW — all attn reads retired above)
  {
    const us* src = AR + A_FC1_W;
#pragma unroll
    for (int i = 0; i < 8; ++i)
      gll16(src + w4 * 4096 + i * 512 + l * 8, sW + w4 * 4096 + i * 512);
  }
  // pair softmax (local; overlaps staging)
  float s0 = sred[h][0][0] + sred[h][1][0];
  float s1 = sred[h][0][1] + sred[h][1][1];
  float mx = fmaxf(s0, s1);
  float e0 = expf(s0 - mx), e1 = expf(s1 - mx);
  float aj0 = e0 / (e0 + e1), aj1 = e1 / (e0 + e1);
  __syncthreads();                             // fc1_w staged

  // ---- fc1 + pairwise LN (register-local) ----
  a0 = 0.f; a1 = 0.f; b0 = 0.f; b1 = 0.f;
  for (int k = 0; k < 128; k += 2){
    float w0 = b2f(sW[k * 128 + d]);
    float w1 = b2f(sW[(k + 1) * 128 + d]);
    a0 += hp[h][0][k] * w0;  a1 += hp[h][0][k + 1] * w1;
    b0 += hp[h][1][k] * w0;  b1 += hp[h][1][k + 1] * w1;
  }
  {
    float fb = b2f(AR[A_FC1_B + d]);
    float y0 = aj0 * (a0 + a1) + fb;
    float y1 = aj1 * (b0 + b1) + fb;
    float mu = 0.5f * (y0 + y1);
    float dv = 0.5f * (y0 - y1);
    float rs = rsqrtf(dv * dv + 1e-5f);
    float g = b2f(AR[A_BN1_G + d]), bb = b2f(AR[A_BN1_B + d]);
    ry[h][0][d] = relu((y0 - mu) * rs * g + bb);
    ry[h][1][d] = relu((y1 - mu) * rs * g + bb);
  }
  __syncthreads();                             // fc1 reads done + ry ready

  // stage fc2_w
  {
    const us* src = AR + A_FC2_W;
#pragma unroll
    for (int i = 0; i < 8; ++i)
      gll16(src + w4 * 4096 + i * 512 + l * 8, sW + w4 * 4096 + i * 512);
  }
  __syncthreads();                             // fc2_w staged

  // ---- fc2 + OUT(ini,res) + csh ----
  a0 = 0.f; a1 = 0.f; b0 = 0.f; b1 = 0.f;
  for (int k = 0; k < 128; k += 2){
    float w0 = b2f(sW[k * 128 + d]);
    float w1 = b2f(sW[(k + 1) * 128 + d]);
    a0 += ry[h][0][k] * w0;  a1 += ry[h][0][k + 1] * w1;
    b0 += ry[h][1][k] * w0;  b1 += ry[h][1][k + 1] * w1;
  }
  {
    float cb = b2f(AR[A_FC2_B + d]);
    float y2_0 = a0 + a1 + cb;
    float y2_1 = b0 + b1 + cb;
    OUT[(long)NPAIR * 128     + p * 128 + d] = y2_0;   // ini (row 0)
    OUT[(long)2 * NPAIR * 128 + p * 128 + d] = y2_1;   // res (row 1)
    csh[h][d]       = y2_0;
    csh[h][128 + d] = y2_1;
  }
  __syncthreads();                             // fc2 reads done + csh ready

  // stage efc1_w rows 0-127 (first 32KB half)
  {
    const us* src = AR + A_EFC1_W;
#pragma unroll
    for (int i = 0; i < 8; ++i)
      gll16(src + w4 * 4096 + i * 512 + l * 8, sW + w4 * 4096 + i * 512);
  }
  __syncthreads();                             // half A staged

  float p20;
  {
    float v0 = 0.f, v1 = 0.f;
    for (int k = 0; k < 128; k += 2){
      v0 += csh[h][k]     * b2f(sW[k * 128 + d]);
      v1 += csh[h][k + 1] * b2f(sW[(k + 1) * 128 + d]);
    }
    p20 = v0 + v1;
  }
  __syncthreads();                             // half-A reads done

  // stage efc1_w rows 128-255 (second 32KB half)
  {
    const us* src = AR + A_EFC1_W + 128 * 128;
#pragma unroll
    for (int i = 0; i < 8; ++i)
      gll16(src + w4 * 4096 + i * 512 + l * 8, sW + w4 * 4096 + i * 512);
  }
  __syncthreads();                             // half B staged

  {
    float v0 = 0.f, v1 = 0.f;
    for (int k = 0; k < 128; k += 2){
      v0 += csh[h][128 + k]     * b2f(sW[k * 128 + d]);
      v1 += csh[h][128 + k + 1] * b2f(sW[(k + 1) * 128 + d]);
    }
    float p21 = v0 + v1;
    Z[p * 128 + d] = p20 + p21 + b2f(AR[A_EFC1_B + d]);
  }
}

// ---------------- K8: batchnorm stats over 4096 rows ----------------
__global__ void k8_stats(const float* __restrict__ Z, float* __restrict__ ST){
  const int c = blockIdx.x, t = threadIdx.x;
  float s = 0.f, s2 = 0.f;
  for (int row = t; row < NPAIR; row += 256){
    float v = Z[(long)row * 128 + c];
    s += v; s2 += v * v;
  }
#pragma unroll
  for (int m = 1; m < 64; m <<= 1){ s += __shfl_xor(s, m, 64); s2 += __shfl_xor(s2, m, 64); }
  __shared__ float red[8];
  if ((t & 63) == 0){ red[t >> 6] = s; red[4 + (t >> 6)] = s2; }
  __syncthreads();
  if (t == 0){
    float S  = red[0] + red[1] + red[2] + red[3];
    float S2 = red[4] + red[5] + red[6] + red[7];
    float mean = S / (float)NPAIR;
    float var  = S2 / (float)NPAIR - mean * mean;
    ST[c]       = mean;
    ST[128 + c] = rsqrtf(var + 1e-5f);
  }
}

// ---------------- K9: bn2 + relu + efc2 — 8 rows per block ----------------
__global__ void k9_final(const float* __restrict__ Z, const float* __restrict__ ST,
                         const us* __restrict__ AR, float* __restrict__ OUT)
{
  const int t = threadIdx.x;
  const int d = t & 127, h = t >> 7;
  const long r0 = (long)blockIdx.x * 8;
  __shared__ float zn[8][132];

  float stm = ST[d], str = ST[128 + d];
  float g = b2f(AR[A_BN2_G + d]), bb = b2f(AR[A_BN2_B + d]);
#pragma unroll
  for (int q = 0; q < 4; ++q){
    int row = h * 4 + q;
    float zv = Z[(r0 + row) * 128 + d];
    zn[row][d] = relu((zv - stm) * str * g + bb);
  }
  __syncthreads();

  float a0[4] = {0.f,0.f,0.f,0.f}, a1[4] = {0.f,0.f,0.f,0.f};
  for (int k = 0; k < 128; k += 2){
    float w0 = b2f(AR[A_EFC2_W + k * 128 + d]);
    float w1 = b2f(AR[A_EFC2_W + (k + 1) * 128 + d]);
#pragma unroll
    for (int q = 0; q < 4; ++q){
      a0[q] += zn[h * 4 + q][k]     * w0;
      a1[q] += zn[h * 4 + q][k + 1] * w1;
    }
  }
  float eb = b2f(AR[A_EFC2_B + d]);
#pragma unroll
  for (int q = 0; q < 4; ++q)
    OUT[(r0 + h * 4 + q) * 128 + d] = a0[q] + a1[q] + eb;
}

extern "C" void kernel_launch(void* const* d_in, const int* in_sizes, int n_in,
                              void* d_out, int out_size, void* d_ws, size_t ws_size,
                              hipStream_t stream)
{
  const float* u2e = (const float*)d_in[0];
  const float* v2e = (const float*)d_in[1];
  const float* r2e = (const float*)d_in[2];
  const int* user_ids     = (const int*)d_in[33];
  const int* hist_items   = (const int*)d_in[34];
  const int* hist_ratings = (const int*)d_in[35];
  const int* soc_neigh    = (const int*)d_in[36];

  char* ws = (char*)d_ws;
  us*    HR  = (us*)(ws + WS_HR);
  float* Z   = (float*)(ws + WS_Z);
  float* ST  = (float*)(ws + WS_ST);
  us*    Wp1 = (us*)(ws + WS_WP1);
  us*    Wp2 = (us*)(ws + WS_WP2);
  us*    WpA = (us*)(ws + WS_WPA);
  us*    WpS = (us*)(ws + WS_WPS);
  us*    AR  = (us*)(ws + WS_AR);
  us*    Ub  = (us*)(ws + WS_UB);
  us*    Vb  = (us*)(ws + WS_VB);
  us*    Rb  = (us*)(ws + WS_RB);
  float* OUT = (float*)d_out;

  const bool big = ws_size >= (size_t)WS2_NEED;

  Prep pr;
  const void* sp[24] = {d_in[4], d_in[6], d_in[8], d_in[9], d_in[11], d_in[12],
                        d_in[14], d_in[15], d_in[17], d_in[18], d_in[19], d_in[20],
                        d_in[21], d_in[22], d_in[23], d_in[24], d_in[25], d_in[26],
                        d_in[27], d_in[28], d_in[29], d_in[30], d_in[31], d_in[32]};
  const unsigned offs[25] = {0,128,256,384,512,33280,33408,33536,33664,66432,
                             66560,82944,83072,99456,99584,99712,99840,116224,
                             116352,149120,149248,149376,149504,165888,166016};
  for (int i = 0; i < 24; ++i) pr.cp[i] = sp[i];
  for (int i = 0; i < 25; ++i) pr.coff[i] = offs[i];
  pr.W1 = (const float*)d_in[3];  pr.W2 = (const float*)d_in[5];
  pr.WA = (const float*)d_in[7];  pr.WS = (const float*)d_in[13];
  pr.u2e = u2e; pr.v2e = v2e; pr.r2e = r2e;

  // ONE preprocessing launch (cvt + pack + tables)
  const int prep_blocks = big ? (PB_CVT + PB_PACK + PB_TAB) : (PB_CVT + PB_PACK);
  k_prep<<<prep_blocks, 256, 0, stream>>>(pr, AR, Wp1, Wp2, WpA, WpS,
                                          Ub, Vb, Rb, big ? 1 : 0);

  if (big){
    k_fused<1><<<NROWS / 2, 512, 0, stream>>>(hist_items, hist_ratings, Vb, Rb,
        user_ids, Ub, soc_neigh, Wp1, Wp2, WpA, WpS, AR, HR);
  } else {
    k_fused<0><<<NROWS / 2, 512, 0, stream>>>(hist_items, hist_ratings, v2e, r2e,
        user_ids, u2e, soc_neigh, Wp1, Wp2, WpA, WpS, AR, HR);
  }

  k7_head<<<NPAIR / 2, 256, 0, stream>>>(HR, AR, OUT, Z);
  k8_stats<<<128, 256, 0, stream>>>(Z, ST);
  k9_final<<<NPAIR / 8, 256, 0, stream>>>(Z, ST, AR, OUT);
}

// Round 15
// 463.808 us; speedup vs baseline: 1.0916x; 1.0916x over previous
//
#include <hip/hip_runtime.h>
#include <hip/hip_bf16.h>
#include <math.h>

// Problem constants
#define NROWS   8192      // 2*B
#define HLEN    50
#define SLEN    32
#define NPAIR   4096

typedef __attribute__((ext_vector_type(8))) short   short8;
typedef __attribute__((ext_vector_type(8))) __bf16  b8;     // MFMA operand type
typedef __attribute__((ext_vector_type(4))) float   f32x4;
typedef unsigned short us;

// ---- bf16 arena offsets (elements) for small fp32 tensors ----
#define A_GV_B1    0
#define A_GV_B2    128
#define A_ATTH_B1  256
#define A_ATTH_W2  384
#define A_ENC_W    512
#define A_ENC_B    33280
#define A_ATTS_B1  33408
#define A_ATTS_W2  33536
#define A_SOC_W    33664
#define A_SOC_B    66432
#define A_ATTN_WA  66560
#define A_ATTN_BA  82944
#define A_FC1_W    83072
#define A_FC1_B    99456
#define A_BN1_G    99584
#define A_BN1_B    99712
#define A_FC2_W    99840
#define A_FC2_B    116224
#define A_EFC1_W   116352
#define A_EFC1_B   149120
#define A_BN2_G    149248
#define A_BN2_B    149376
#define A_EFC2_W   149504
#define A_EFC2_B   165888
#define A_TOTAL    166016

// workspace layout (bytes)
#define WS_HR    0u          // 8192*128 bf16 = 2097152
#define WS_Z     2097152u    // 4096*128 f32  = 2097152
#define WS_ST    4194304u    // 256 f32 + pad
#define WS_WP1   4195328u    // 32768 bf16
#define WS_WP2   4260864u    // 16384 bf16
#define WS_WPA   4293632u    // 32768 bf16
#define WS_WPS   4359168u    // 32768 bf16
#define WS_AR    4424704u    // 166016 bf16 -> end 4756736
#define WS_UB    4757504u    // 100000*128 bf16 = 25600000
#define WS_VB    30357504u   // 50000*128 bf16  = 12800000
#define WS_RB    43157504u   // 10*128 bf16     = 2560
#define WS2_NEED 43160064u

// k_prep block ranges (256 threads each)
#define PB_CVT   649         // ceil(166016/256)
#define PB_PACK  56          // 14336/256
#define PB_TAB   9376        // ceil(2400160/256)

__device__ __forceinline__ float b2f(us u){
  unsigned int x = ((unsigned int)u) << 16; float f;
  __builtin_memcpy(&f, &x, 4); return f;
}
// accurate RNE (one-time weight/table conversion)
__device__ __forceinline__ us f2b(float f){
  unsigned int x; __builtin_memcpy(&x, &f, 4);
  return (us)((x + 0x7fffu + ((x >> 16) & 1u)) >> 16);
}
// cheap round-half-up (activation hot path)
__device__ __forceinline__ us f2bc(float f){
  unsigned int x; __builtin_memcpy(&x, &f, 4);
  return (us)((x + 0x8000u) >> 16);
}
__device__ __forceinline__ float relu(float x){ return 0.5f * (x + fabsf(x)); }

__device__ __forceinline__ b8 f8_to_b8(const float* f){
  short8 v;
#pragma unroll
  for (int j = 0; j < 8; ++j) v[j] = (short)f2bc(f[j]);
  return __builtin_bit_cast(b8, v);
}

// ---- async global->LDS staging (16B per lane, wave-uniform LDS base) ----
typedef __attribute__((address_space(3))) unsigned char lds_b;
typedef const __attribute__((address_space(1))) unsigned char glob_b;

__device__ __forceinline__ void gll16(const us* g, us* d){
  __builtin_amdgcn_global_load_lds((glob_b*)g, (lds_b*)d, 16, 0, 0);
}

// Stage one 8KB K-slice of lane-linear packed weights into ring buffer p
// (p in 0..2), 8 waves cooperating: wave w8 copies us range [w8*512, +512)
// with ONE global_load_lds (16B/lane) -> 1 vmem op per wave per stage.
__device__ __forceinline__ void stage8k(const us* __restrict__ W, us* sB,
                                        int w8, int l, int ks, int p){
  const us* src = W + ((long)ks << 12) + (w8 << 9) + (l << 3);
  us* dst = sB + p * 4096 + (w8 << 9);
  gll16(src, dst);
}

// Depth-2 counted-wait phase boundary (T4: never drain to 0 mid-loop).
// Each wave has <=2 stages outstanding; vmcnt(1) completes the OLDEST
// (this phase's buffer) while the next stage stays in flight across the
// barrier. sched_barrier(0) pins pre-barrier MFMAs above (rule #18).
#define PHASE_SYNC() do {                                   \
    asm volatile("s_waitcnt vmcnt(1)" ::: "memory");        \
    __builtin_amdgcn_s_barrier();                           \
    asm volatile("" ::: "memory");                          \
    __builtin_amdgcn_sched_barrier(0);                      \
  } while (0)

// ---- ONE preprocessing launch: cvt arena + pack MFMA weights + bf16 tables ----
struct Prep {
  const void* cp[24]; unsigned coff[25];            // cvt sources
  const float *W1, *W2, *WA, *WS;                   // pack sources
  const float *u2e, *v2e, *r2e;                     // table sources
};
__global__ void k_prep(Prep pr, us* __restrict__ AR,
                       us* __restrict__ Wp1, us* __restrict__ Wp2,
                       us* __restrict__ WpA, us* __restrict__ WpS,
                       us* __restrict__ Ub, us* __restrict__ Vb,
                       us* __restrict__ Rb, int do_tab)
{
  const int b = blockIdx.x, t = threadIdx.x;
  if (b < PB_CVT){                                  // ---- arena cvt ----
    int i = b * 256 + t;
    if (i >= A_TOTAL) return;
    int s = 0;
    while (i >= (int)pr.coff[s + 1]) ++s;
    AR[i] = f2b(((const float*)pr.cp[s])[i - (int)pr.coff[s]]);
  } else if (b < PB_CVT + PB_PACK){                 // ---- MFMA pack ----
    int g = (b - PB_CVT) * 256 + t;                 // g < 14336 always
    const float* W; us* Wp; int loc;
    if      (g <  4096){ W = pr.W1; Wp = Wp1; loc = g; }
    else if (g <  6144){ W = pr.W2; Wp = Wp2; loc = g - 4096; }
    else if (g < 10240){ W = pr.WA; Wp = WpA; loc = g - 6144; }
    else               { W = pr.WS; Wp = WpS; loc = g - 10240; }
    int lane16 = loc & 15, quad = (loc >> 4) & 3, nt = (loc >> 6) & 7, kseg = loc >> 9;
#pragma unroll
    for (int j = 0; j < 8; ++j)
      Wp[(long)loc * 8 + j] = f2b(W[(kseg * 32 + quad * 8 + j) * 128 + nt * 16 + lane16]);
  } else {                                          // ---- bf16 tables ----
    if (!do_tab) return;
    int i = (b - PB_CVT - PB_PACK) * 256 + t;
    const float* s; us* d; int loc;
    if      (i < 1600000){ s = pr.u2e; d = Ub; loc = i; }
    else if (i < 2400000){ s = pr.v2e; d = Vb; loc = i - 1600000; }
    else if (i < 2400160){ s = pr.r2e; d = Rb; loc = i - 2400000; }
    else return;
    const float* sp = s + (long)loc * 8;
    short8 w;
#pragma unroll
    for (int j = 0; j < 8; ++j) w[j] = (short)f2b(sp[j]);
    *(short8*)(d + (long)loc * 8) = w;
  }
}

// ============ fused history+social path: one block per TWO rows ============
// Ring buffer g%3; stage for g+2 issued at phase g (depth-2).
// NOTE (R12 lesson): do NOT fuse the k7 head in here — the head's many-block
// TLP as a separate kernel far outweighs the 2MB HR round-trip it saves.
// NOTE (R14 lesson): the head is TLP-bound, not weight-traffic-bound — LDS
// weight staging in k7 also regresses (-42us). Keep k7 in its R8 form.
template<int TAB>
__global__ __launch_bounds__(512, 4)
void k_fused(const int* __restrict__ items, const int* __restrict__ ratings,
             const void* __restrict__ vt, const void* __restrict__ rt,
             const int* __restrict__ uids, const void* __restrict__ ut,
             const int* __restrict__ soc,
             const us* __restrict__ Wp1, const us* __restrict__ Wp2,
             const us* __restrict__ WpA, const us* __restrict__ WpS,
             const us* __restrict__ AR, us* __restrict__ HR)
{
  const int t = threadIdx.x;
  const int rr = t >> 8, tt = t & 255;          // row group, id within group
  const int r = blockIdx.x * 2 + rr;
  const int w = tt >> 6;                        // wave within row group 0..3
  const int w8 = t >> 6;                        // global wave 0..7 (staging)
  const int l = t & 63, lane16 = l & 15, quad = l >> 4;
  const int tc = tt & 127, th = tt >> 7;        // split-k id within row
  const long ubase = (long)uids[r] * 128;

  __shared__ __align__(16) us sX[2][64 * 136];  // per-row X1->X2; later sN
  __shared__ __align__(16) us sB[3 * 4096];     // ring of 3 x 8KB B slices
  __shared__ float esh[2][64], a_sh[2][64], part[2][256], xin[2][256];

  // prologue: slices 0,1 in flight before the A-fragment gather
  stage8k(Wp1, sB, w8, l, 0, 0);                // g=0 -> buf 0
  stage8k(Wp1, sB, w8, l, 1, 1);                // g=1 -> buf 1

  const int arow = w * 16 + lane16;
  const bool av = arow < HLEN;
  const int it_i = av ? items[r * HLEN + arow]   : 0;
  const int rt_i = av ? ratings[r * HLEN + arow] : 0;

  // ---- A fragments for GEMM1 (direct gather) ----
  b8 af[8];
#pragma unroll
  for (int ks = 0; ks < 8; ++ks){
    b8 a;
    if constexpr (TAB){
      const us* ap = (ks < 4)
          ? (const us*)vt + (long)it_i * 128 + ks * 32 + quad * 8
          : (const us*)rt + (long)rt_i * 128 + (ks - 4) * 32 + quad * 8;
      a = *(const b8*)ap;
    } else {
      const float* ap = (ks < 4)
          ? (const float*)vt + (long)it_i * 128 + ks * 32 + quad * 8
          : (const float*)rt + (long)rt_i * 128 + (ks - 4) * 32 + quad * 8;
      a = f8_to_b8(ap);
    }
    if (!av) a = __builtin_bit_cast(b8, (short8)0);
    af[ks] = a;
  }
  // u-row fragments (broadcast row; reused in GEMM3 + soc GEMM)
  b8 uf[4];
#pragma unroll
  for (int ks = 0; ks < 4; ++ks){
    if constexpr (TAB)
      uf[ks] = *(const b8*)((const us*)ut + ubase + ks * 32 + quad * 8);
    else
      uf[ks] = f8_to_b8((const float*)ut + ubase + ks * 32 + quad * 8);
  }

  // ---- GEMM1: X1 = relu([v|r] @ W1 + b1), K=256, g=0..7 ----
  {
    f32x4 acc[8];
#pragma unroll
    for (int nt = 0; nt < 8; ++nt) acc[nt] = (f32x4){0.f,0.f,0.f,0.f};
#pragma unroll
    for (int ks = 0; ks < 8; ++ks){
      PHASE_SYNC();                             // oldest stage (ks) landed
      if      (ks < 6)  stage8k(Wp1, sB, w8, l, ks + 2, (ks + 2) % 3);
      else if (ks == 6) stage8k(Wp2, sB, w8, l, 0, 2);   // g'=8  -> buf 2
      else              stage8k(Wp2, sB, w8, l, 1, 0);   // g'=9  -> buf 0
      const us* bb = sB + (ks % 3) * 4096 + l * 8;
#pragma unroll
      for (int nt = 0; nt < 8; ++nt)
        acc[nt] = __builtin_amdgcn_mfma_f32_16x16x32_bf16(
            af[ks], *(const b8*)(bb + nt * 512), acc[nt], 0, 0, 0);
    }
#pragma unroll
    for (int nt = 0; nt < 8; ++nt){
      int col = nt * 16 + lane16;
      float bbv = b2f(AR[A_GV_B1 + col]);
#pragma unroll
      for (int rg = 0; rg < 4; ++rg)
        sX[rr][(w * 16 + quad * 4 + rg) * 136 + col] = f2bc(relu(acc[nt][rg] + bbv));
    }
  }
  // no barrier: each wave reads/writes only its own 16-row slice of sX[rr]

  // ---- GEMM2: X2 = relu(X1 @ W2 + b2), K=128, g=8..11, in place ----
  {
    b8 a2[4];
#pragma unroll
    for (int ks = 0; ks < 4; ++ks)
      a2[ks] = *(const b8*)(sX[rr] + arow * 136 + ks * 32 + quad * 8);
    f32x4 acc[8];
#pragma unroll
    for (int nt = 0; nt < 8; ++nt) acc[nt] = (f32x4){0.f,0.f,0.f,0.f};
#pragma unroll
    for (int ks = 0; ks < 4; ++ks){
      PHASE_SYNC();
      if      (ks < 2)  stage8k(Wp2, sB, w8, l, ks + 2, (ks + 10) % 3); // g'=10,11
      else if (ks == 2) stage8k(WpA, sB, w8, l, 0, 0);   // g'=12 -> buf 0
      else              stage8k(WpA, sB, w8, l, 1, 1);   // g'=13 -> buf 1
      const us* bb = sB + ((8 + ks) % 3) * 4096 + l * 8;
#pragma unroll
      for (int nt = 0; nt < 8; ++nt)
        acc[nt] = __builtin_amdgcn_mfma_f32_16x16x32_bf16(
            a2[ks], *(const b8*)(bb + nt * 512), acc[nt], 0, 0, 0);
    }
#pragma unroll
    for (int nt = 0; nt < 8; ++nt){
      int col = nt * 16 + lane16;
      float bbv = b2f(AR[A_GV_B2 + col]);
#pragma unroll
      for (int rg = 0; rg < 4; ++rg)
        sX[rr][(w * 16 + quad * 4 + rg) * 136 + col] = f2bc(relu(acc[nt][rg] + bbv));
    }
  }

  // ---- GEMM3: e = relu([X2|u] @ WA + bA) @ w2, K=256, g=12..19 ----
  {
    b8 a3[8];
#pragma unroll
    for (int ks = 0; ks < 4; ++ks)
      a3[ks] = *(const b8*)(sX[rr] + arow * 136 + ks * 32 + quad * 8);
#pragma unroll
    for (int ks = 0; ks < 4; ++ks) a3[4 + ks] = uf[ks];
    f32x4 acc[8];
#pragma unroll
    for (int nt = 0; nt < 8; ++nt) acc[nt] = (f32x4){0.f,0.f,0.f,0.f};
#pragma unroll
    for (int ks = 0; ks < 8; ++ks){
      PHASE_SYNC();
      if      (ks < 6)  stage8k(WpA, sB, w8, l, ks + 2, (ks + 14) % 3);
      else if (ks == 6) stage8k(WpS, sB, w8, l, 0, 2);   // g'=20 -> buf 2
      else              stage8k(WpS, sB, w8, l, 1, 0);   // g'=21 -> buf 0
      const us* bb = sB + ((12 + ks) % 3) * 4096 + l * 8;
#pragma unroll
      for (int nt = 0; nt < 8; ++nt)
        acc[nt] = __builtin_amdgcn_mfma_f32_16x16x32_bf16(
            a3[ks], *(const b8*)(bb + nt * 512), acc[nt], 0, 0, 0);
    }
    float pr[4] = {0.f, 0.f, 0.f, 0.f};
#pragma unroll
    for (int nt = 0; nt < 8; ++nt){             // hoisted bias/w2 loads
      int col = nt * 16 + lane16;
      float bbv = b2f(AR[A_ATTH_B1 + col]);
      float wwv = b2f(AR[A_ATTH_W2 + col]);
#pragma unroll
      for (int rg = 0; rg < 4; ++rg)
        pr[rg] += relu(acc[nt][rg] + bbv) * wwv;
    }
#pragma unroll
    for (int rg = 0; rg < 4; ++rg){
      float p = pr[rg];
      p += __shfl_xor(p, 1, 64);
      p += __shfl_xor(p, 2, 64);
      p += __shfl_xor(p, 4, 64);
      p += __shfl_xor(p, 8, 64);
      if (lane16 == 0) esh[rr][w * 16 + quad * 4 + rg] = p;
    }
  }
  __syncthreads();                              // B1: esh complete (+WpS s0,s1 land)

  if (tt < 64){                                 // softmax over 50 (waves 0,4)
    float e = (tt < HLEN) ? esh[rr][tt] : -1e30f;
    float mx = e;
#pragma unroll
    for (int m = 1; m < 64; m <<= 1) mx = fmaxf(mx, __shfl_xor(mx, m, 64));
    float ex = (tt < HLEN) ? expf(e - mx) : 0.f;
    float s = ex;
#pragma unroll
    for (int m = 1; m < 64; m <<= 1) s += __shfl_xor(s, m, 64);
    if (tt < HLEN) a_sh[rr][tt] = ex / s;
  }
  __syncthreads();                              // B2: a_sh

  {                                             // agg split-k (25 rows/half)
    float s = 0.f;
    for (int h = th * 25; h < th * 25 + 25; ++h)
      s += a_sh[rr][h] * b2f(sX[rr][h * 136 + tc]);
    part[rr][tt] = s;
  }
  __syncthreads();                              // B3: part
  if (tt < 128){
    xin[rr][tt] = TAB ? b2f(((const us*)ut)[ubase + tt]) : ((const float*)ut)[ubase + tt];
    xin[rr][128 + tt] = part[rr][tt] + part[rr][128 + tt];
  }
  __syncthreads();                              // B4: xin

  // enc split-k (column-major AR reads: coalesced across lanes) + soc gather
  {
    float s0 = 0.f, s1 = 0.f;
    const int kb = th * 128;
    for (int k = 0; k < 128; k += 2){
      s0 += xin[rr][kb + k]     * b2f(AR[A_ENC_W + (kb + k)     * 128 + tc]);
      s1 += xin[rr][kb + k + 1] * b2f(AR[A_ENC_W + (kb + k + 1) * 128 + tc]);
    }
    part[rr][tt] = s0 + s1;
#pragma unroll
    for (int it = 0; it < 2; ++it){             // sN: 32 x 128 gather per row
      int idx = tt * 8 + it * 2048;
      int row = idx >> 7, col = idx & 127;
      long eb = (long)soc[r * SLEN + row] * 128 + col;
      short8 v;
      if constexpr (TAB) v = *(const short8*)((const us*)ut + eb);
      else               v = __builtin_bit_cast(short8, f8_to_b8((const float*)ut + eb));
      *(short8*)(sX[rr] + row * 136 + col) = v;
    }
  }
  __syncthreads();                              // B5: enc part + sN staged

  float hhv = 0.f;                              // HH value (register, tt<128)
  if (tt < 128)
    hhv = relu(part[rr][tt] + part[rr][128 + tt] + b2f(AR[A_ENC_B + tt]));

  // ---- soc GEMM: es = relu([nf|u] @ WS + bS) @ w2s, M=32, K=256, g=20..27 ----
  {
    const int mt = w & 1, nh = w >> 1;
    const int arow2 = mt * 16 + lane16;
    b8 aS[8];
#pragma unroll
    for (int ks = 0; ks < 4; ++ks)
      aS[ks] = *(const b8*)(sX[rr] + arow2 * 136 + ks * 32 + quad * 8);
#pragma unroll
    for (int ks = 0; ks < 4; ++ks) aS[4 + ks] = uf[ks];
    f32x4 acc[4];
#pragma unroll
    for (int nt = 0; nt < 4; ++nt) acc[nt] = (f32x4){0.f,0.f,0.f,0.f};
#pragma unroll
    for (int ks = 0; ks < 8; ++ks){
      PHASE_SYNC();
      if (ks < 6) stage8k(WpS, sB, w8, l, ks + 2, (ks + 22) % 3);
      const us* bb = sB + ((20 + ks) % 3) * 4096 + (nh << 11) + l * 8;  // nh half
#pragma unroll
      for (int nt = 0; nt < 4; ++nt)
        acc[nt] = __builtin_amdgcn_mfma_f32_16x16x32_bf16(
            aS[ks], *(const b8*)(bb + nt * 512), acc[nt], 0, 0, 0);
    }
    float pr[4] = {0.f, 0.f, 0.f, 0.f};
#pragma unroll
    for (int nt = 0; nt < 4; ++nt){             // hoisted bias/w2 loads
      int n = nh * 64 + nt * 16 + lane16;
      float bbv = b2f(AR[A_ATTS_B1 + n]);
      float wwv = b2f(AR[A_ATTS_W2 + n]);
#pragma unroll
      for (int rg = 0; rg < 4; ++rg)
        pr[rg] += relu(acc[nt][rg] + bbv) * wwv;
    }
#pragma unroll
    for (int rg = 0; rg < 4; ++rg){
      float p = pr[rg];
      p += __shfl_xor(p, 1, 64);
      p += __shfl_xor(p, 2, 64);
      p += __shfl_xor(p, 4, 64);
      p += __shfl_xor(p, 8, 64);
      if (lane16 == 0) esh[rr][nh * 32 + mt * 16 + quad * 4 + rg] = p;
    }
  }
  __syncthreads();                              // B6: soc esh

  if (tt < 32){                                 // softmax over 32
    float e = esh[rr][tt] + esh[rr][32 + tt];
    float mx = e;
#pragma unroll
    for (int m = 1; m < 32; m <<= 1) mx = fmaxf(mx, __shfl_xor(mx, m, 32));
    float ex = expf(e - mx);
    float s = ex;
#pragma unroll
    for (int m = 1; m < 32; m <<= 1) s += __shfl_xor(s, m, 32);
    a_sh[rr][tt] = ex / s;
  }
  __syncthreads();                              // B7

  {                                             // agg_s split-k
    float s = 0.f;
    for (int h = th * 16; h < th * 16 + 16; ++h)
      s += a_sh[rr][h] * b2f(sX[rr][h * 136 + tc]);
    part[rr][tt] = s;
  }
  __syncthreads();                              // B8
  if (tt < 128){
    xin[rr][tt]       = hhv;
    xin[rr][128 + tt] = part[rr][tt] + part[rr][128 + tt];
  }
  __syncthreads();                              // B9

  {                                             // soc layer split-k (column AR)
    float s0 = 0.f, s1 = 0.f;
    const int kb = th * 128;
    for (int k = 0; k < 128; k += 2){
      s0 += xin[rr][kb + k]     * b2f(AR[A_SOC_W + (kb + k)     * 128 + tc]);
      s1 += xin[rr][kb + k + 1] * b2f(AR[A_SOC_W + (kb + k + 1) * 128 + tc]);
    }
    part[rr][tt] = s0 + s1;
  }
  __syncthreads();                              // B10
  if (tt < 128)
    HR[(long)r * 128 + tt] =
        f2bc(relu(part[rr][tt] + part[rr][128 + tt] + b2f(AR[A_SOC_B + tt])));
}

// ---------------- K7: fusion head (attn, fc1, LN, fc2, efc1) ----------------
// 128 threads/block: thread d computes BOTH pair-rows for column d, so each
// weight column is loaded ONCE. Accumulation order unchanged -> bit-identical.
// Kept as a SEPARATE kernel with column-major L2 weight reads: its 4096-block
// TLP is the latency hiding (R12 fusion: +77us; R14 LDS staging: +42us).
__global__ void k7_head(const us* __restrict__ HR, const us* __restrict__ AR,
                        float* __restrict__ OUT, float* __restrict__ Z)
{
  const int i = blockIdx.x, t = threadIdx.x;   // 128 threads
  __shared__ float hp[2][128], ry[2][128], csh[256];
  __shared__ float sred[2][2];                 // [wave][j]

  hp[0][t] = b2f(HR[(long)(2 * i)     * 128 + t]);
  hp[1][t] = b2f(HR[(long)(2 * i + 1) * 128 + t]);
  __syncthreads();

  // attn mat-vec: shared weight loads, both rows
  float a0 = 0.f, a1 = 0.f, b0 = 0.f, b1 = 0.f;
  for (int k = 0; k < 128; k += 2){
    float w0 = b2f(AR[A_ATTN_WA + k * 128 + t]);
    float w1 = b2f(AR[A_ATTN_WA + (k + 1) * 128 + t]);
    a0 += hp[0][k] * w0;  a1 += hp[0][k + 1] * w1;
    b0 += hp[1][k] * w0;  b1 += hp[1][k + 1] * w1;
  }
  float ba = b2f(AR[A_ATTN_BA + t]);
  float p0 = tanhf(a0 + a1) * ba;
  float p1 = tanhf(b0 + b1) * ba;
#pragma unroll
  for (int m = 1; m < 64; m <<= 1){ p0 += __shfl_xor(p0, m, 64); p1 += __shfl_xor(p1, m, 64); }
  if ((t & 63) == 0){ sred[t >> 6][0] = p0; sred[t >> 6][1] = p1; }
  __syncthreads();

  float s0 = sred[0][0] + sred[1][0], s1 = sred[0][1] + sred[1][1];
  float mx = fmaxf(s0, s1);
  float e0 = expf(s0 - mx), e1 = expf(s1 - mx);
  float aj0 = e0 / (e0 + e1), aj1 = e1 / (e0 + e1);

  // fc1 mat-vec: shared weight loads, both rows
  a0 = 0.f; a1 = 0.f; b0 = 0.f; b1 = 0.f;
  for (int k = 0; k < 128; k += 2){
    float w0 = b2f(AR[A_FC1_W + k * 128 + t]);
    float w1 = b2f(AR[A_FC1_W + (k + 1) * 128 + t]);
    a0 += hp[0][k] * w0;  a1 += hp[0][k + 1] * w1;
    b0 += hp[1][k] * w0;  b1 += hp[1][k + 1] * w1;
  }
  float fb = b2f(AR[A_FC1_B + t]);
  float y0 = aj0 * (a0 + a1) + fb;
  float y1 = aj1 * (b0 + b1) + fb;

  // pairwise LN — register-local (both rows in-thread)
  {
    float mu = 0.5f * (y0 + y1);
    float dv = 0.5f * (y0 - y1);
    float rs = rsqrtf(dv * dv + 1e-5f);
    float g = b2f(AR[A_BN1_G + t]), bb = b2f(AR[A_BN1_B + t]);
    ry[0][t] = relu((y0 - mu) * rs * g + bb);
    ry[1][t] = relu((y1 - mu) * rs * g + bb);
  }
  __syncthreads();

  // fc2 mat-vec: shared weight loads, both rows
  a0 = 0.f; a1 = 0.f; b0 = 0.f; b1 = 0.f;
  for (int k = 0; k < 128; k += 2){
    float w0 = b2f(AR[A_FC2_W + k * 128 + t]);
    float w1 = b2f(AR[A_FC2_W + (k + 1) * 128 + t]);
    a0 += ry[0][k] * w0;  a1 += ry[0][k + 1] * w1;
    b0 += ry[1][k] * w0;  b1 += ry[1][k + 1] * w1;
  }
  float cb = b2f(AR[A_FC2_B + t]);
  float y2_0 = a0 + a1 + cb;
  float y2_1 = b0 + b1 + cb;
  OUT[(long)NPAIR * 128     + (long)i * 128 + t] = y2_0;   // ini (row 0)
  OUT[(long)2 * NPAIR * 128 + (long)i * 128 + t] = y2_1;   // res (row 1)
  csh[t]       = y2_0;
  csh[128 + t] = y2_1;
  __syncthreads();

  // efc1: K=256, exact kh-half split preserved (p2[0] + p2[1] + bias)
  {
    float v0 = 0.f, v1 = 0.f;
    for (int k = 0; k < 128; k += 2){
      v0 += csh[k]     * b2f(AR[A_EFC1_W + k * 128 + t]);
      v1 += csh[k + 1] * b2f(AR[A_EFC1_W + (k + 1) * 128 + t]);
    }
    float p20 = v0 + v1;
    v0 = 0.f; v1 = 0.f;
    for (int k = 0; k < 128; k += 2){
      v0 += csh[128 + k]     * b2f(AR[A_EFC1_W + (128 + k) * 128 + t]);
      v1 += csh[128 + k + 1] * b2f(AR[A_EFC1_W + (128 + k + 1) * 128 + t]);
    }
    float p21 = v0 + v1;
    Z[(long)i * 128 + t] = p20 + p21 + b2f(AR[A_EFC1_B + t]);
  }
}

// ---------------- K8: batchnorm stats over 4096 rows ----------------
__global__ void k8_stats(const float* __restrict__ Z, float* __restrict__ ST){
  const int c = blockIdx.x, t = threadIdx.x;
  float s = 0.f, s2 = 0.f;
  for (int row = t; row < NPAIR; row += 256){
    float v = Z[(long)row * 128 + c];
    s += v; s2 += v * v;
  }
#pragma unroll
  for (int m = 1; m < 64; m <<= 1){ s += __shfl_xor(s, m, 64); s2 += __shfl_xor(s2, m, 64); }
  __shared__ float red[8];
  if ((t & 63) == 0){ red[t >> 6] = s; red[4 + (t >> 6)] = s2; }
  __syncthreads();
  if (t == 0){
    float S  = red[0] + red[1] + red[2] + red[3];
    float S2 = red[4] + red[5] + red[6] + red[7];
    float mean = S / (float)NPAIR;
    float var  = S2 / (float)NPAIR - mean * mean;
    ST[c]       = mean;
    ST[128 + c] = rsqrtf(var + 1e-5f);
  }
}

// ---------------- K9: bn2 + relu + efc2 — 8 rows per block ----------------
__global__ void k9_final(const float* __restrict__ Z, const float* __restrict__ ST,
                         const us* __restrict__ AR, float* __restrict__ OUT)
{
  const int t = threadIdx.x;
  const int d = t & 127, h = t >> 7;
  const long r0 = (long)blockIdx.x * 8;
  __shared__ float zn[8][132];

  float stm = ST[d], str = ST[128 + d];
  float g = b2f(AR[A_BN2_G + d]), bb = b2f(AR[A_BN2_B + d]);
#pragma unroll
  for (int q = 0; q < 4; ++q){
    int row = h * 4 + q;
    float zv = Z[(r0 + row) * 128 + d];
    zn[row][d] = relu((zv - stm) * str * g + bb);
  }
  __syncthreads();

  float a0[4] = {0.f,0.f,0.f,0.f}, a1[4] = {0.f,0.f,0.f,0.f};
  for (int k = 0; k < 128; k += 2){
    float w0 = b2f(AR[A_EFC2_W + k * 128 + d]);
    float w1 = b2f(AR[A_EFC2_W + (k + 1) * 128 + d]);
#pragma unroll
    for (int q = 0; q < 4; ++q){
      a0[q] += zn[h * 4 + q][k]     * w0;
      a1[q] += zn[h * 4 + q][k + 1] * w1;
    }
  }
  float eb = b2f(AR[A_EFC2_B + d]);
#pragma unroll
  for (int q = 0; q < 4; ++q)
    OUT[(r0 + h * 4 + q) * 128 + d] = a0[q] + a1[q] + eb;
}

extern "C" void kernel_launch(void* const* d_in, const int* in_sizes, int n_in,
                              void* d_out, int out_size, void* d_ws, size_t ws_size,
                              hipStream_t stream)
{
  const float* u2e = (const float*)d_in[0];
  const float* v2e = (const float*)d_in[1];
  const float* r2e = (const float*)d_in[2];
  const int* user_ids     = (const int*)d_in[33];
  const int* hist_items   = (const int*)d_in[34];
  const int* hist_ratings = (const int*)d_in[35];
  const int* soc_neigh    = (const int*)d_in[36];

  char* ws = (char*)d_ws;
  us*    HR  = (us*)(ws + WS_HR);
  float* Z   = (float*)(ws + WS_Z);
  float* ST  = (float*)(ws + WS_ST);
  us*    Wp1 = (us*)(ws + WS_WP1);
  us*    Wp2 = (us*)(ws + WS_WP2);
  us*    WpA = (us*)(ws + WS_WPA);
  us*    WpS = (us*)(ws + WS_WPS);
  us*    AR  = (us*)(ws + WS_AR);
  us*    Ub  = (us*)(ws + WS_UB);
  us*    Vb  = (us*)(ws + WS_VB);
  us*    Rb  = (us*)(ws + WS_RB);
  float* OUT = (float*)d_out;

  const bool big = ws_size >= (size_t)WS2_NEED;

  Prep pr;
  const void* sp[24] = {d_in[4], d_in[6], d_in[8], d_in[9], d_in[11], d_in[12],
                        d_in[14], d_in[15], d_in[17], d_in[18], d_in[19], d_in[20],
                        d_in[21], d_in[22], d_in[23], d_in[24], d_in[25], d_in[26],
                        d_in[27], d_in[28], d_in[29], d_in[30], d_in[31], d_in[32]};
  const unsigned offs[25] = {0,128,256,384,512,33280,33408,33536,33664,66432,
                             66560,82944,83072,99456,99584,99712,99840,116224,
                             116352,149120,149248,149376,149504,165888,166016};
  for (int i = 0; i < 24; ++i) pr.cp[i] = sp[i];
  for (int i = 0; i < 25; ++i) pr.coff[i] = offs[i];
  pr.W1 = (const float*)d_in[3];  pr.W2 = (const float*)d_in[5];
  pr.WA = (const float*)d_in[7];  pr.WS = (const float*)d_in[13];
  pr.u2e = u2e; pr.v2e = v2e; pr.r2e = r2e;

  // ONE preprocessing launch (cvt + pack + tables)
  const int prep_blocks = big ? (PB_CVT + PB_PACK + PB_TAB) : (PB_CVT + PB_PACK);
  k_prep<<<prep_blocks, 256, 0, stream>>>(pr, AR, Wp1, Wp2, WpA, WpS,
                                          Ub, Vb, Rb, big ? 1 : 0);

  if (big){
    k_fused<1><<<NROWS / 2, 512, 0, stream>>>(hist_items, hist_ratings, Vb, Rb,
        user_ids, Ub, soc_neigh, Wp1, Wp2, WpA, WpS, AR, HR);
  } else {
    k_fused<0><<<NROWS / 2, 512, 0, stream>>>(hist_items, hist_ratings, v2e, r2e,
        user_ids, u2e, soc_neigh, Wp1, Wp2, WpA, WpS, AR, HR);
  }

  k7_head<<<NPAIR, 128, 0, stream>>>(HR, AR, OUT, Z);
  k8_stats<<<128, 256, 0, stream>>>(Z, ST);
  k9_final<<<NPAIR / 8, 256, 0, stream>>>(Z, ST, AR, OUT);
}